// Round 1
// baseline (338.076 us; speedup 1.0000x reference)
//
#include <hip/hip_runtime.h>
#include <math.h>

#define E_TOTAL 32768
#define NUM_NODES 4096
#define EPB 8              // edges per block
#define SCALE 0.70710678118654752f

// so2_linear term structure at L_in=L_out=1:
// row0 = x0@W0 + x2@W2 ; row1 = x1@W4 + x3@W5 ; row2 = x0@W1 + x2@W3 ; row3 = x3@W4 - x1@W5

// q-side tables: per output row m, two (input_row, weight, sign) terms
__device__ const int QA1[4] = {0, 1, 0, 3};
__device__ const int QW1[4] = {0, 4, 1, 4};
__device__ const int QA2[4] = {2, 3, 2, 1};
__device__ const int QW2[4] = {2, 5, 3, 5};
__device__ const float QS2[4] = {1.f, 1.f, 1.f, -1.f};

// k-side tables: per weight slot w, up to two (input_row -> output_row, sign) terms
__device__ const int KA1[6] = {0, 0, 2, 2, 1, 3};
__device__ const int KM1[6] = {0, 2, 0, 2, 1, 1};
__device__ const int KA2[6] = {0, 0, 0, 0, 3, 1};
__device__ const int KM2[6] = {0, 0, 0, 0, 3, 3};
__device__ const int KS2[6] = {0, 0, 0, 0, 1, -1};   // 0 = no second term

__global__ __launch_bounds__(256) void fused_z_kernel(
    const float* __restrict__ x_q, const float* __restrict__ x_k,
    const float* __restrict__ emb, const float* __restrict__ W_q,
    const float* __restrict__ W_p, float* __restrict__ z_out)
{
    __shared__ float emb_s[EPB][64];     // 2 KB
    __shared__ float xk_s[EPB][64];      // 2 KB  (4 rows x 16 ch, flattened)
    __shared__ float xq_s[EPB][64];      // 2 KB
    __shared__ float Wq_s[3072];         // 12 KB
    __shared__ float q_s[EPB][128];      // 4 KB  (4 rows x 32 out)
    __shared__ float k_s[EPB][128];      // 4 KB
    __shared__ float wk_s[EPB][512];     // 16 KB (one weight slot: 16 x 32)

    const int t = threadIdx.x;
    const int e0 = blockIdx.x * EPB;

    // ---- stage inputs (all contiguous, coalesced) ----
    ((float*)emb_s)[t]       = emb[(size_t)e0 * 64 + t];
    ((float*)emb_s)[t + 256] = emb[(size_t)e0 * 64 + t + 256];
    ((float*)xk_s)[t]        = x_k[(size_t)e0 * 64 + t];
    ((float*)xk_s)[t + 256]  = x_k[(size_t)e0 * 64 + t + 256];
    ((float*)xq_s)[t]        = x_q[(size_t)e0 * 64 + t];
    ((float*)xq_s)[t + 256]  = x_q[(size_t)e0 * 64 + t + 256];
#pragma unroll
    for (int i = 0; i < 12; ++i) Wq_s[i * 256 + t] = W_q[i * 256 + t];
#pragma unroll
    for (int i = 0; i < 4; ++i) ((float*)k_s)[i * 256 + t] = 0.f;
    __syncthreads();

    // ---- q = so2_linear(x_q, W_q): thread handles (e, o), loops m ----
    {
        const int e = t >> 5, o = t & 31;
#pragma unroll
        for (int m = 0; m < 4; ++m) {
            const float* xa = &xq_s[e][QA1[m] * 16];
            const float* wa = &Wq_s[QW1[m] * 512 + o];
            const float* xb = &xq_s[e][QA2[m] * 16];
            const float* wb = &Wq_s[QW2[m] * 512 + o];
            float s1 = 0.f, s2 = 0.f;
#pragma unroll
            for (int c = 0; c < 16; ++c) s1 += xa[c] * wa[c * 32];
#pragma unroll
            for (int c = 0; c < 16; ++c) s2 += xb[c] * wb[c * 32];
            q_s[e][m * 32 + o] = s1 + QS2[m] * s2;
        }
    }

    // ---- fused W_k GEMM + k accumulation, one weight slot at a time ----
    const float* wp_base = W_p + 2 * t;   // + w*512 + d*3072
    for (int w = 0; w < 6; ++w) {
        float acc0[EPB], acc1[EPB];
#pragma unroll
        for (int e = 0; e < EPB; ++e) { acc0[e] = 0.f; acc1[e] = 0.f; }
        const float* wp = wp_base + w * 512;
        for (int d = 0; d < 64; d += 4) {
            float4 em[EPB];
#pragma unroll
            for (int e = 0; e < EPB; ++e) em[e] = *(const float4*)&emb_s[e][d];
#pragma unroll
            for (int dd = 0; dd < 4; ++dd) {
                float2 wv = *(const float2*)(wp + (size_t)(d + dd) * 3072);
#pragma unroll
                for (int e = 0; e < EPB; ++e) {
                    float em_c = (dd == 0) ? em[e].x : (dd == 1) ? em[e].y
                               : (dd == 2) ? em[e].z : em[e].w;
                    acc0[e] += em_c * wv.x;
                    acc1[e] += em_c * wv.y;
                }
            }
        }
        __syncthreads();   // previous slot's k-accum reads done before overwrite
#pragma unroll
        for (int e = 0; e < EPB; ++e) {
            wk_s[e][2 * t]     = acc0[e];
            wk_s[e][2 * t + 1] = acc1[e];
        }
        __syncthreads();
        // k accumulation for this slot: thread handles (e, o)
        {
            const int e = t >> 5, o = t & 31;
            const int a1 = KA1[w], m1 = KM1[w];
            float s = 0.f;
#pragma unroll
            for (int c = 0; c < 16; ++c) s += xk_s[e][a1 * 16 + c] * wk_s[e][c * 32 + o];
            k_s[e][m1 * 32 + o] += s;
            const int s2 = KS2[w];
            if (s2 != 0) {
                const int a2 = KA2[w], m2 = KM2[w];
                float sb = 0.f;
#pragma unroll
                for (int c = 0; c < 16; ++c) sb += xk_s[e][a2 * 16 + c] * wk_s[e][c * 32 + o];
                k_s[e][m2 * 32 + o] += (s2 > 0) ? sb : -sb;
            }
        }
    }
    __syncthreads();

    // ---- z[e,h] = scale * sum_{m,j} q[e,m,h*8+j] * k[e,m,h*8+j] ----
    if (t < EPB * 4) {
        const int e = t >> 2, h = t & 3;
        float s = 0.f;
#pragma unroll
        for (int m = 0; m < 4; ++m)
#pragma unroll
            for (int j = 0; j < 8; ++j)
                s += q_s[e][m * 32 + h * 8 + j] * k_s[e][m * 32 + h * 8 + j];
        z_out[(size_t)(e0 + e) * 4 + h] = s * SCALE;
    }
}

__global__ __launch_bounds__(64) void segment_softmax_kernel(
    const float* __restrict__ z, const int* __restrict__ index,
    float* __restrict__ out)
{
    const int n = blockIdx.x;
    // lower_bound(index, n) and lower_bound(index, n+1) over sorted index
    int lo = 0, hi = E_TOTAL;
    while (lo < hi) { int mid = (lo + hi) >> 1; if (index[mid] < n) lo = mid + 1; else hi = mid; }
    const int start = lo;
    hi = E_TOTAL;
    while (lo < hi) { int mid = (lo + hi) >> 1; if (index[mid] < n + 1) lo = mid + 1; else hi = mid; }
    const int end = lo;
    if (start >= end) return;

    const int lane = threadIdx.x;
    const int h = lane & 3, eo = lane >> 2;

    float m = -INFINITY;
    for (int e = start + eo; e < end; e += 16) m = fmaxf(m, z[(size_t)e * 4 + h]);
#pragma unroll
    for (int s = 4; s < 64; s <<= 1) m = fmaxf(m, __shfl_xor(m, s));

    float sum = 0.f;
    for (int e = start + eo; e < end; e += 16) sum += __expf(z[(size_t)e * 4 + h] - m);
#pragma unroll
    for (int s = 4; s < 64; s <<= 1) sum += __shfl_xor(sum, s);

    const float inv = 1.f / sum;
    for (int e = start + eo; e < end; e += 16)
        out[(size_t)e * 4 + h] = __expf(z[(size_t)e * 4 + h] - m) * inv;
}

extern "C" void kernel_launch(void* const* d_in, const int* in_sizes, int n_in,
                              void* d_out, int out_size, void* d_ws, size_t ws_size,
                              hipStream_t stream) {
    const float* x_q  = (const float*)d_in[0];
    const float* x_k  = (const float*)d_in[1];
    const float* emb  = (const float*)d_in[2];
    const int*   index = (const int*)d_in[3];
    const float* W_q  = (const float*)d_in[4];
    const float* W_p  = (const float*)d_in[5];
    float* out = (float*)d_out;
    float* z   = (float*)d_ws;   // E_TOTAL * 4 floats = 512 KB

    fused_z_kernel<<<E_TOTAL / EPB, 256, 0, stream>>>(x_q, x_k, emb, W_q, W_p, z);
    segment_softmax_kernel<<<NUM_NODES, 64, 0, stream>>>(z, index, out);
}

// Round 2
// 151.213 us; speedup vs baseline: 2.2358x; 2.2358x over previous
//
#include <hip/hip_runtime.h>
#include <math.h>

#define E_TOTAL 32768
#define NUM_NODES 4096
#define SCALE 0.70710678118654752f

typedef __attribute__((ext_vector_type(8))) short bfrag;
typedef __attribute__((ext_vector_type(16))) float facc;

__device__ inline unsigned short f2bf(float f) {
  unsigned int u = __float_as_uint(f);
  unsigned int r = (u + 0x7FFFu + ((u >> 16) & 1u)) >> 16;
  return (unsigned short)r;
}
__device__ inline float bf2f(unsigned short s) {
  return __uint_as_float(((unsigned int)s) << 16);
}
__device__ inline void cvt8(const float* v, bfrag& hi, bfrag& lo) {
#pragma unroll
  for (int i = 0; i < 8; ++i) {
    unsigned short h = f2bf(v[i]);
    hi[i] = (short)h;
    lo[i] = (short)f2bf(v[i] - bf2f(h));
  }
}

// ---------------------------------------------------------------------------
// Prepack: W_p -> A-operand bf16 hi/lo fragments, per n-tile nt = c*6 + w
//   frag layout per nt: [ks(4)][hl(2)][lane(64)][j(8)] bf16  (8 KB)
//   element = W_p[d][w*512 + c*32 + (lane&31)], d = ks*16 + (lane>>5)*8 + j
// Blocks 96..102: W_q slots (slot 6 = -W_q[5]): [slot][hl][lane][j]
// ---------------------------------------------------------------------------
__global__ __launch_bounds__(256) void prepack_kernel(
    const float* __restrict__ Wp, const float* __restrict__ Wq,
    unsigned short* __restrict__ fragWp, unsigned short* __restrict__ fragWq)
{
  const int b = blockIdx.x, t = threadIdx.x;
  if (b < 96) {
    __shared__ unsigned short lds[4096];
    const int c = b / 6, w = b - c * 6;
    const int colbase = w * 512 + c * 32;
    const int cl = t & 31, dg = t >> 5;
#pragma unroll
    for (int i = 0; i < 8; ++i) {
      const int d = dg * 8 + i;
      const float v = Wp[(size_t)d * 3072 + colbase + cl];
      const unsigned short hi = f2bf(v);
      const unsigned short lo = f2bf(v - bf2f(hi));
      const int ks = d >> 4;
      const int lane = ((d >> 3) & 1) * 32 + cl;
      const int j = d & 7;
      lds[(ks * 2 + 0) * 512 + lane * 8 + j] = hi;
      lds[(ks * 2 + 1) * 512 + lane * 8 + j] = lo;
    }
    __syncthreads();
    unsigned short* dst = fragWp + (size_t)b * 4096;
    ((uint4*)dst)[t] = ((const uint4*)lds)[t];
    ((uint4*)dst)[t + 256] = ((const uint4*)lds)[t + 256];
  } else {
    const int slot = b - 96;
    const int w = (slot == 6) ? 5 : slot;
    const float sgn = (slot == 6) ? -1.f : 1.f;
    for (int tt = t; tt < 512; tt += 256) {
      const int lane = tt >> 3, j = tt & 7;
      const int o = lane & 31, c = (lane >> 5) * 8 + j;
      const float v = sgn * Wq[(size_t)(w * 16 + c) * 32 + o];
      const unsigned short hi = f2bf(v);
      const unsigned short lo = f2bf(v - bf2f(hi));
      fragWq[slot * 1024 + lane * 8 + j] = hi;
      fragWq[slot * 1024 + 512 + lane * 8 + j] = lo;
    }
  }
}

// ---------------------------------------------------------------------------
// Segment offsets: offs[n] = first edge e with index[e] >= n (index sorted)
// ---------------------------------------------------------------------------
__global__ __launch_bounds__(256) void boundary_kernel(
    const int* __restrict__ index, int* __restrict__ offs)
{
  const int t = blockIdx.x * 256 + threadIdx.x;
  if (t >= E_TOTAL) return;
  const int cur = index[t];
  const int prev = (t == 0) ? -1 : index[t - 1];
  for (int n = prev + 1; n <= cur; ++n) offs[n] = t;
  if (t == E_TOTAL - 1)
    for (int n = cur + 1; n <= NUM_NODES; ++n) offs[n] = E_TOTAL;
}

// ---------------------------------------------------------------------------
// Main: per wave 32 edges. D = (W_p^T tile) x (emb^T), 3-term split bf16 MFMA,
// contract C (col=edge, row=o) into k accumulators via so2 table, then q via
// MFMA in the same layout, z = sum q*k.
// ---------------------------------------------------------------------------
__global__ __launch_bounds__(128) void main_kernel(
    const float* __restrict__ x_q, const float* __restrict__ x_k,
    const float* __restrict__ emb,
    const unsigned short* __restrict__ fragWp,
    const unsigned short* __restrict__ fragWq,
    float* __restrict__ z)
{
  __shared__ unsigned short fragbuf[2][2][4][2][512];  // 32 KB dbuf: [p][ni][ks][hl][lane*8+j]
  __shared__ float xk_t[64][64];                       // 16 KB: [d][e_local]

  const int t = threadIdx.x;
  const int lane = t & 63, wv = t >> 6;
  const int col = lane & 31, half = lane >> 5;
  const int eb = blockIdx.x * 64;
  const int el = wv * 32 + col;
  const int e = eb + el;

  // stage x_k transposed (thread t: row t>>1, d-half t&1) — conflict-free reads later
  {
    const int er = t >> 1, dh = (t & 1) * 32;
    const float* src = x_k + (size_t)(eb + er) * 64 + dh;
#pragma unroll
    for (int i = 0; i < 8; ++i) {
      float4 v = *(const float4*)(src + i * 4);
      xk_t[dh + i * 4 + 0][er] = v.x;
      xk_t[dh + i * 4 + 1][er] = v.y;
      xk_t[dh + i * 4 + 2][er] = v.z;
      xk_t[dh + i * 4 + 3][er] = v.w;
    }
  }

  // emb B-fragments, split hi/lo: B[k=d][col=e], d = ks*16 + half*8 + j
  bfrag ebh[4], ebl[4];
#pragma unroll
  for (int ks = 0; ks < 4; ++ks) {
    float tmp[8];
    *(float4*)&tmp[0] = *(const float4*)(emb + (size_t)e * 64 + ks * 16 + half * 8);
    *(float4*)&tmp[4] = *(const float4*)(emb + (size_t)e * 64 + ks * 16 + half * 8 + 4);
    cvt8(tmp, ebh[ks], ebl[ks]);
  }

  facc ka0 = {0}, ka1 = {0}, ka2 = {0}, ka3 = {0};

  // stage chunk 0 (2 n-tiles = 16 KB; each wave half)
  {
    const unsigned short* gp = fragWp + wv * 4096 + lane * 8;
    unsigned short* lp = &fragbuf[0][0][0][0][0] + wv * 4096;
#pragma unroll
    for (int i = 0; i < 8; ++i)
      __builtin_amdgcn_global_load_lds(
          (const __attribute__((address_space(1))) unsigned int*)(gp + i * 512),
          (__attribute__((address_space(3))) unsigned int*)(lp + i * 512), 16, 0, 0);
  }
  __syncthreads();

  float xkc0 = 0.f, xkc1 = 0.f, xkc2 = 0.f, xkc3 = 0.f;

  for (int it = 0; it < 48; ++it) {
    const int p = it & 1;
    if (it < 47) {
      const unsigned short* gp = fragWp + (size_t)(it + 1) * 8192 + wv * 4096 + lane * 8;
      unsigned short* lp = &fragbuf[p ^ 1][0][0][0][0] + wv * 4096;
#pragma unroll
      for (int i = 0; i < 8; ++i)
        __builtin_amdgcn_global_load_lds(
            (const __attribute__((address_space(1))) unsigned int*)(gp + i * 512),
            (__attribute__((address_space(3))) unsigned int*)(lp + i * 512), 16, 0, 0);
    }
#pragma unroll
    for (int ni = 0; ni < 2; ++ni) {
      const int nt = it * 2 + ni;
      const int c = nt / 6, w = nt - c * 6;
      if (w == 0) {  // refresh x_k column c (broadcast across halves)
        xkc0 = xk_t[c][el & 63];
        xkc1 = xk_t[16 + c][el & 63];
        xkc2 = xk_t[32 + c][el & 63];
        xkc3 = xk_t[48 + c][el & 63];
      }
      facc cc = {0.f};
#pragma unroll
      for (int ks = 0; ks < 4; ++ks) {
        bfrag wh = *(const bfrag*)&fragbuf[p][ni][ks][0][lane * 8];
        bfrag wl = *(const bfrag*)&fragbuf[p][ni][ks][1][lane * 8];
        cc = __builtin_amdgcn_mfma_f32_32x32x16_bf16(wh, ebh[ks], cc, 0, 0, 0);
        cc = __builtin_amdgcn_mfma_f32_32x32x16_bf16(wh, ebl[ks], cc, 0, 0, 0);
        cc = __builtin_amdgcn_mfma_f32_32x32x16_bf16(wl, ebh[ks], cc, 0, 0, 0);
      }
      // so2 contraction: w0:x0->m0 w1:x0->m2 w2:x2->m0 w3:x2->m2
      //                  w4:x1->m1,x3->m3  w5:x3->m1,-x1->m3
      if (w < 4) {
        const float xv = (w >= 2) ? xkc2 : xkc0;
        if (w & 1) {
#pragma unroll
          for (int r = 0; r < 16; ++r) ka2[r] = fmaf(xv, cc[r], ka2[r]);
        } else {
#pragma unroll
          for (int r = 0; r < 16; ++r) ka0[r] = fmaf(xv, cc[r], ka0[r]);
        }
      } else if (w == 4) {
#pragma unroll
        for (int r = 0; r < 16; ++r) ka1[r] = fmaf(xkc1, cc[r], ka1[r]);
#pragma unroll
        for (int r = 0; r < 16; ++r) ka3[r] = fmaf(xkc3, cc[r], ka3[r]);
      } else {
#pragma unroll
        for (int r = 0; r < 16; ++r) ka1[r] = fmaf(xkc3, cc[r], ka1[r]);
#pragma unroll
        for (int r = 0; r < 16; ++r) ka3[r] = fmaf(-xkc1, cc[r], ka3[r]);
      }
    }
    __syncthreads();
  }

  // ---- q via MFMA (same C layout as ka), fold into z
  bfrag xqh[4], xql[4];
#pragma unroll
  for (int a = 0; a < 4; ++a) {
    float tmp[8];
    *(float4*)&tmp[0] = *(const float4*)(x_q + (size_t)e * 64 + a * 16 + half * 8);
    *(float4*)&tmp[4] = *(const float4*)(x_q + (size_t)e * 64 + a * 16 + half * 8 + 4);
    cvt8(tmp, xqh[a], xql[a]);
  }
  float zp0 = 0.f, zp1 = 0.f, zp2 = 0.f, zp3 = 0.f;
  const int QA1[4] = {0, 1, 0, 3}, QS1[4] = {0, 4, 1, 4};
  const int QA2[4] = {2, 3, 2, 1}, QS2[4] = {2, 5, 3, 6};  // slot 6 = -Wq[5]
#pragma unroll
  for (int m = 0; m < 4; ++m) {
    facc qa = {0.f};
#pragma unroll
    for (int tm = 0; tm < 2; ++tm) {
      const int a = tm ? QA2[m] : QA1[m];
      const int sl = tm ? QS2[m] : QS1[m];
      bfrag wh, wl;
      *(uint4*)&wh = *(const uint4*)(fragWq + sl * 1024 + lane * 8);
      *(uint4*)&wl = *(const uint4*)(fragWq + sl * 1024 + 512 + lane * 8);
      qa = __builtin_amdgcn_mfma_f32_32x32x16_bf16(wh, xqh[a], qa, 0, 0, 0);
      qa = __builtin_amdgcn_mfma_f32_32x32x16_bf16(wh, xql[a], qa, 0, 0, 0);
      qa = __builtin_amdgcn_mfma_f32_32x32x16_bf16(wl, xqh[a], qa, 0, 0, 0);
    }
    const facc& km = (m == 0) ? ka0 : (m == 1) ? ka1 : (m == 2) ? ka2 : ka3;
#pragma unroll
    for (int r = 0; r < 16; ++r) {
      const float v = qa[r] * km[r];
      if (r < 4) zp0 += v;
      else if (r < 8) zp1 += v;
      else if (r < 12) zp2 += v;
      else zp3 += v;
    }
  }
  zp0 += __shfl_xor(zp0, 32);
  zp1 += __shfl_xor(zp1, 32);
  zp2 += __shfl_xor(zp2, 32);
  zp3 += __shfl_xor(zp3, 32);
  if (half == 0) {
    float4 o = {zp0 * SCALE, zp1 * SCALE, zp2 * SCALE, zp3 * SCALE};
    *(float4*)&z[(size_t)e * 4] = o;
  }
}

// ---------------------------------------------------------------------------
__global__ __launch_bounds__(256) void softmax_kernel(
    const float* __restrict__ z, const int* __restrict__ offs,
    float* __restrict__ out)
{
  const int node = blockIdx.x * 4 + (threadIdx.x >> 6);
  const int lane = threadIdx.x & 63;
  const int start = offs[node], end = offs[node + 1];
  if (start >= end) return;
  const int h = lane & 3, eo = lane >> 2;
  float m = -INFINITY;
  for (int e = start + eo; e < end; e += 16) m = fmaxf(m, z[(size_t)e * 4 + h]);
#pragma unroll
  for (int s = 4; s < 64; s <<= 1) m = fmaxf(m, __shfl_xor(m, s));
  float sum = 0.f;
  for (int e = start + eo; e < end; e += 16) sum += __expf(z[(size_t)e * 4 + h] - m);
#pragma unroll
  for (int s = 4; s < 64; s <<= 1) sum += __shfl_xor(sum, s);
  const float inv = 1.f / sum;
  for (int e = start + eo; e < end; e += 16)
    out[(size_t)e * 4 + h] = __expf(z[(size_t)e * 4 + h] - m) * inv;
}

extern "C" void kernel_launch(void* const* d_in, const int* in_sizes, int n_in,
                              void* d_out, int out_size, void* d_ws, size_t ws_size,
                              hipStream_t stream) {
  const float* x_q = (const float*)d_in[0];
  const float* x_k = (const float*)d_in[1];
  const float* emb = (const float*)d_in[2];
  const int* index = (const int*)d_in[3];
  const float* W_q = (const float*)d_in[4];
  const float* W_p = (const float*)d_in[5];
  float* out = (float*)d_out;

  char* ws = (char*)d_ws;
  float* z = (float*)ws;                                          // 524288 B
  int* offs = (int*)(ws + 524288);                                // 16388 B (pad 32 KB)
  unsigned short* fragWp = (unsigned short*)(ws + 524288 + 32768);            // 786432 B
  unsigned short* fragWq = (unsigned short*)(ws + 524288 + 32768 + 786432);   // 14336 B

  prepack_kernel<<<103, 256, 0, stream>>>(W_p, W_q, fragWp, fragWq);
  boundary_kernel<<<128, 256, 0, stream>>>(index, offs);
  main_kernel<<<512, 128, 0, stream>>>(x_q, x_k, emb, fragWp, fragWq, z);
  softmax_kernel<<<1024, 256, 0, stream>>>(z, offs, out);
}

// Round 3
// 130.581 us; speedup vs baseline: 2.5890x; 1.1580x over previous
//
#include <hip/hip_runtime.h>
#include <math.h>

#define E_TOTAL 32768
#define NUM_NODES 4096
#define SCALE 0.70710678118654752f

typedef __attribute__((ext_vector_type(8))) short bfrag;
typedef __attribute__((ext_vector_type(16))) float facc;

__device__ inline unsigned short f2bf(float f) {
  unsigned int u = __float_as_uint(f);
  unsigned int r = (u + 0x7FFFu + ((u >> 16) & 1u)) >> 16;
  return (unsigned short)r;
}
__device__ inline float bf2f(unsigned short s) {
  return __uint_as_float(((unsigned int)s) << 16);
}
__device__ inline void cvt8(const float* v, bfrag& hi, bfrag& lo) {
#pragma unroll
  for (int i = 0; i < 8; ++i) {
    unsigned short h = f2bf(v[i]);
    hi[i] = (short)h;
    lo[i] = (short)f2bf(v[i] - bf2f(h));
  }
}

// ---------------------------------------------------------------------------
// Combined prep: blocks 0..95 W_p frags, 96..102 W_q frags, 103..230 offsets
// frag layout per n-tile nt=c*6+w: [ks(4)][hl(2)][lane(64)][j(8)] bf16 (8 KB)
//   element = W_p[d][w*512 + c*32 + (lane&31)], d = ks*16 + (lane>>5)*8 + j
// ---------------------------------------------------------------------------
__global__ __launch_bounds__(256) void prep_kernel(
    const float* __restrict__ Wp, const float* __restrict__ Wq,
    const int* __restrict__ index,
    unsigned short* __restrict__ fragWp, unsigned short* __restrict__ fragWq,
    int* __restrict__ offs)
{
  const int b = blockIdx.x, t = threadIdx.x;
  if (b < 96) {
    __shared__ unsigned short lds[4096];
    const int c = b / 6, w = b - c * 6;
    const int colbase = w * 512 + c * 32;
    const int cl = t & 31, dg = t >> 5;
#pragma unroll
    for (int i = 0; i < 8; ++i) {
      const int d = dg * 8 + i;
      const float v = Wp[(size_t)d * 3072 + colbase + cl];
      const unsigned short hi = f2bf(v);
      const unsigned short lo = f2bf(v - bf2f(hi));
      const int ks = d >> 4;
      const int lane = ((d >> 3) & 1) * 32 + cl;
      const int j = d & 7;
      lds[(ks * 2 + 0) * 512 + lane * 8 + j] = hi;
      lds[(ks * 2 + 1) * 512 + lane * 8 + j] = lo;
    }
    __syncthreads();
    unsigned short* dst = fragWp + (size_t)b * 4096;
    ((uint4*)dst)[t] = ((const uint4*)lds)[t];
    ((uint4*)dst)[t + 256] = ((const uint4*)lds)[t + 256];
  } else if (b < 103) {
    const int slot = b - 96;
    const int w = (slot == 6) ? 5 : slot;
    const float sgn = (slot == 6) ? -1.f : 1.f;
    for (int tt = t; tt < 512; tt += 256) {
      const int lane = tt >> 3, j = tt & 7;
      const int o = lane & 31, c = (lane >> 5) * 8 + j;
      const float v = sgn * Wq[(size_t)(w * 16 + c) * 32 + o];
      const unsigned short hi = f2bf(v);
      const unsigned short lo = f2bf(v - bf2f(hi));
      fragWq[slot * 1024 + lane * 8 + j] = hi;
      fragWq[slot * 1024 + 512 + lane * 8 + j] = lo;
    }
  } else {
    const int tg = (b - 103) * 256 + t;
    if (tg >= E_TOTAL) return;
    const int cur = index[tg];
    const int prev = (tg == 0) ? -1 : index[tg - 1];
    for (int n = prev + 1; n <= cur; ++n) offs[n] = tg;
    if (tg == E_TOTAL - 1)
      for (int n = cur + 1; n <= NUM_NODES; ++n) offs[n] = E_TOTAL;
  }
}

// ---------------------------------------------------------------------------
// Main: 4 waves/block, 64 edges/block. Wave pair pg owns 32 edges; waves in a
// pair split n-tiles by parity (pr0: w even, pr1: w odd; z linear in k).
// 3 independent MFMA chains per tile. Partial z reduced via LDS.
// ---------------------------------------------------------------------------
__global__ __launch_bounds__(256, 2) void main_kernel(
    const float* __restrict__ x_q, const float* __restrict__ x_k,
    const float* __restrict__ emb,
    const unsigned short* __restrict__ fragWp,
    const unsigned short* __restrict__ fragWq,
    float* __restrict__ z)
{
  __shared__ unsigned short fragbuf[2][8192];  // 32 KB dbuf: 2 tiles/chunk
  __shared__ float xk_t[64][65];               // 16.25 KB, padded
  __shared__ float zred[4][32][4];             // 2 KB

  const int t = threadIdx.x;
  const int lane = t & 63, wv = t >> 6;
  const int pr = wv & 1, pg = wv >> 1;
  const int col = lane & 31, half = lane >> 5;
  const int eb = blockIdx.x * 64;
  const int el = pg * 32 + col;
  const int e = eb + el;

  // stage x_k transposed: thread t -> edge t>>2, d-quarter (t&3)*16
  {
    const int er = t >> 2, dq = (t & 3) * 16;
    const float* src = x_k + (size_t)(eb + er) * 64 + dq;
#pragma unroll
    for (int i = 0; i < 4; ++i) {
      float4 v = *(const float4*)(src + i * 4);
      xk_t[dq + i * 4 + 0][er] = v.x;
      xk_t[dq + i * 4 + 1][er] = v.y;
      xk_t[dq + i * 4 + 2][er] = v.z;
      xk_t[dq + i * 4 + 3][er] = v.w;
    }
  }

  // emb B-fragments hi/lo: B[k=d][col=e], d = ks*16 + half*8 + j
  bfrag ebh[4], ebl[4];
#pragma unroll
  for (int ks = 0; ks < 4; ++ks) {
    float tmp[8];
    *(float4*)&tmp[0] = *(const float4*)(emb + (size_t)e * 64 + ks * 16 + half * 8);
    *(float4*)&tmp[4] = *(const float4*)(emb + (size_t)e * 64 + ks * 16 + half * 8 + 4);
    cvt8(tmp, ebh[ks], ebl[ks]);
  }

  facc ka0 = {0}, ka1 = {0}, ka2 = {0}, ka3 = {0};

  // stage chunk 0: 16 KB, each wave 4 KB
  {
    const unsigned short* gp = fragWp + wv * 2048 + lane * 8;
    unsigned short* lp = fragbuf[0] + wv * 2048;
#pragma unroll
    for (int i = 0; i < 4; ++i)
      __builtin_amdgcn_global_load_lds(
          (const __attribute__((address_space(1))) unsigned int*)(gp + i * 512),
          (__attribute__((address_space(3))) unsigned int*)(lp + i * 512), 16, 0, 0);
  }
  __syncthreads();

  float xkc0 = 0.f, xkc1 = 0.f, xkc2 = 0.f, xkc3 = 0.f;

  for (int c16 = 0; c16 < 16; ++c16) {
#pragma unroll
    for (int j = 0; j < 3; ++j) {
      const int it = c16 * 3 + j;
      const int p = it & 1;
      if (it < 47) {  // prefetch next chunk into other buffer
        const unsigned short* gp =
            fragWp + (size_t)(it + 1) * 8192 + wv * 2048 + lane * 8;
        unsigned short* lp = fragbuf[p ^ 1] + wv * 2048;
#pragma unroll
        for (int i = 0; i < 4; ++i)
          __builtin_amdgcn_global_load_lds(
              (const __attribute__((address_space(1))) unsigned int*)(gp + i * 512),
              (__attribute__((address_space(3))) unsigned int*)(lp + i * 512), 16, 0, 0);
      }
      if (j == 0) {
        xkc0 = xk_t[c16][el];
        xkc1 = xk_t[16 + c16][el];
        xkc2 = xk_t[32 + c16][el];
        xkc3 = xk_t[48 + c16][el];
      }
      // this wave's tile: nt = it*2 + pr -> w = 2*j + pr
      const unsigned short* fb = fragbuf[p] + pr * 4096;
      facc cc0 = {0.f}, cc1 = {0.f}, cc2 = {0.f};  // 3 independent chains of 4
#pragma unroll
      for (int ks = 0; ks < 4; ++ks) {
        bfrag wh = *(const bfrag*)(fb + (ks * 2 + 0) * 512 + lane * 8);
        bfrag wl = *(const bfrag*)(fb + (ks * 2 + 1) * 512 + lane * 8);
        cc0 = __builtin_amdgcn_mfma_f32_32x32x16_bf16(wh, ebh[ks], cc0, 0, 0, 0);
        cc1 = __builtin_amdgcn_mfma_f32_32x32x16_bf16(wh, ebl[ks], cc1, 0, 0, 0);
        cc2 = __builtin_amdgcn_mfma_f32_32x32x16_bf16(wl, ebh[ks], cc2, 0, 0, 0);
      }
      // so2 contraction. pr0: w0:x0->m0 w2:x2->m0 w4:x1->m1,x3->m3
      //                  pr1: w1:x0->m2 w3:x2->m2 w5:x3->m1,-x1->m3
      if (j < 2) {
        const float xv = (j == 0) ? xkc0 : xkc2;
        if (pr == 0) {
#pragma unroll
          for (int r = 0; r < 16; ++r)
            ka0[r] = fmaf(xv, cc0[r] + cc1[r] + cc2[r], ka0[r]);
        } else {
#pragma unroll
          for (int r = 0; r < 16; ++r)
            ka2[r] = fmaf(xv, cc0[r] + cc1[r] + cc2[r], ka2[r]);
        }
      } else {
        if (pr == 0) {
#pragma unroll
          for (int r = 0; r < 16; ++r) {
            const float s = cc0[r] + cc1[r] + cc2[r];
            ka1[r] = fmaf(xkc1, s, ka1[r]);
            ka3[r] = fmaf(xkc3, s, ka3[r]);
          }
        } else {
#pragma unroll
          for (int r = 0; r < 16; ++r) {
            const float s = cc0[r] + cc1[r] + cc2[r];
            ka1[r] = fmaf(xkc3, s, ka1[r]);
            ka3[r] = fmaf(-xkc1, s, ka3[r]);
          }
        }
      }
      __syncthreads();
    }
  }

  // ---- q via MFMA (same C layout as ka), partial z, cross-parity reduce
  bfrag xqh[4], xql[4];
#pragma unroll
  for (int a = 0; a < 4; ++a) {
    float tmp[8];
    *(float4*)&tmp[0] = *(const float4*)(x_q + (size_t)e * 64 + a * 16 + half * 8);
    *(float4*)&tmp[4] = *(const float4*)(x_q + (size_t)e * 64 + a * 16 + half * 8 + 4);
    cvt8(tmp, xqh[a], xql[a]);
  }
  float zp0 = 0.f, zp1 = 0.f, zp2 = 0.f, zp3 = 0.f;
  const int QA1[4] = {0, 1, 0, 3}, QS1[4] = {0, 4, 1, 4};
  const int QA2[4] = {2, 3, 2, 1}, QS2[4] = {2, 5, 3, 6};  // slot 6 = -Wq[5]
#pragma unroll
  for (int m = 0; m < 4; ++m) {
    facc qa = {0.f};
#pragma unroll
    for (int tm = 0; tm < 2; ++tm) {
      const int a = tm ? QA2[m] : QA1[m];
      const int sl = tm ? QS2[m] : QS1[m];
      bfrag wh, wl;
      *(uint4*)&wh = *(const uint4*)(fragWq + sl * 1024 + lane * 8);
      *(uint4*)&wl = *(const uint4*)(fragWq + sl * 1024 + 512 + lane * 8);
      qa = __builtin_amdgcn_mfma_f32_32x32x16_bf16(wh, xqh[a], qa, 0, 0, 0);
      qa = __builtin_amdgcn_mfma_f32_32x32x16_bf16(wh, xql[a], qa, 0, 0, 0);
      qa = __builtin_amdgcn_mfma_f32_32x32x16_bf16(wl, xqh[a], qa, 0, 0, 0);
    }
    const facc& km = (m == 0) ? ka0 : (m == 1) ? ka1 : (m == 2) ? ka2 : ka3;
#pragma unroll
    for (int r = 0; r < 16; ++r) {
      const float v = qa[r] * km[r];
      if (r < 4) zp0 += v;
      else if (r < 8) zp1 += v;
      else if (r < 12) zp2 += v;
      else zp3 += v;
    }
  }
  zp0 += __shfl_xor(zp0, 32);
  zp1 += __shfl_xor(zp1, 32);
  zp2 += __shfl_xor(zp2, 32);
  zp3 += __shfl_xor(zp3, 32);
  if (half == 0) {
    float4 v = {zp0, zp1, zp2, zp3};
    *(float4*)&zred[wv][col][0] = v;
  }
  __syncthreads();
  if (pr == 0 && half == 0) {
    float4 a = *(const float4*)&zred[wv][col][0];
    float4 b = *(const float4*)&zred[wv ^ 1][col][0];
    float4 o = {(a.x + b.x) * SCALE, (a.y + b.y) * SCALE,
                (a.z + b.z) * SCALE, (a.w + b.w) * SCALE};
    *(float4*)&z[(size_t)e * 4] = o;
  }
}

// ---------------------------------------------------------------------------
__global__ __launch_bounds__(256) void softmax_kernel(
    const float* __restrict__ z, const int* __restrict__ offs,
    float* __restrict__ out)
{
  const int node = blockIdx.x * 4 + (threadIdx.x >> 6);
  const int lane = threadIdx.x & 63;
  const int start = offs[node], end = offs[node + 1];
  if (start >= end) return;
  const int h = lane & 3, eo = lane >> 2;
  float m = -INFINITY;
  for (int e = start + eo; e < end; e += 16) m = fmaxf(m, z[(size_t)e * 4 + h]);
#pragma unroll
  for (int s = 4; s < 64; s <<= 1) m = fmaxf(m, __shfl_xor(m, s));
  float sum = 0.f;
  for (int e = start + eo; e < end; e += 16) sum += __expf(z[(size_t)e * 4 + h] - m);
#pragma unroll
  for (int s = 4; s < 64; s <<= 1) sum += __shfl_xor(sum, s);
  const float inv = 1.f / sum;
  for (int e = start + eo; e < end; e += 16)
    out[(size_t)e * 4 + h] = __expf(z[(size_t)e * 4 + h] - m) * inv;
}

extern "C" void kernel_launch(void* const* d_in, const int* in_sizes, int n_in,
                              void* d_out, int out_size, void* d_ws, size_t ws_size,
                              hipStream_t stream) {
  const float* x_q = (const float*)d_in[0];
  const float* x_k = (const float*)d_in[1];
  const float* emb = (const float*)d_in[2];
  const int* index = (const int*)d_in[3];
  const float* W_q = (const float*)d_in[4];
  const float* W_p = (const float*)d_in[5];
  float* out = (float*)d_out;

  char* ws = (char*)d_ws;
  float* z = (float*)ws;                                                    // 524288 B
  int* offs = (int*)(ws + 524288);                                          // 16388 B (pad 32 KB)
  unsigned short* fragWp = (unsigned short*)(ws + 524288 + 32768);          // 786432 B
  unsigned short* fragWq = (unsigned short*)(ws + 524288 + 32768 + 786432); // 14336 B

  prep_kernel<<<231, 256, 0, stream>>>(W_p, W_q, index, fragWp, fragWq, offs);
  main_kernel<<<512, 256, 0, stream>>>(x_q, x_k, emb, fragWp, fragWq, z);
  softmax_kernel<<<1024, 256, 0, stream>>>(z, offs, out);
}

// Round 4
// 123.946 us; speedup vs baseline: 2.7276x; 1.0535x over previous
//
#include <hip/hip_runtime.h>
#include <math.h>

#define E_TOTAL 32768
#define NUM_NODES 4096
#define SCALE 0.70710678118654752f

typedef __attribute__((ext_vector_type(8))) short bfrag;
typedef __attribute__((ext_vector_type(16))) float facc;

__device__ inline unsigned short f2bf(float f) {
  unsigned int u = __float_as_uint(f);
  unsigned int r = (u + 0x7FFFu + ((u >> 16) & 1u)) >> 16;
  return (unsigned short)r;
}
__device__ inline float bf2f(unsigned short s) {
  return __uint_as_float(((unsigned int)s) << 16);
}
__device__ inline void cvt8(const float* v, bfrag& hi, bfrag& lo) {
#pragma unroll
  for (int i = 0; i < 8; ++i) {
    unsigned short h = f2bf(v[i]);
    hi[i] = (short)h;
    lo[i] = (short)f2bf(v[i] - bf2f(h));
  }
}

// ---------------------------------------------------------------------------
// Combined prep: blocks 0..95 W_p frags, 96..102 W_q frags, 103..230 offsets
// frag layout per n-tile nt=c*6+w: [ks(4)][hl(2)][lane(64)][j(8)] bf16 (8 KB)
//   element = W_p[d][w*512 + c*32 + (lane&31)], d = ks*16 + (lane>>5)*8 + j
// ---------------------------------------------------------------------------
__global__ __launch_bounds__(256) void prep_kernel(
    const float* __restrict__ Wp, const float* __restrict__ Wq,
    const int* __restrict__ index,
    unsigned short* __restrict__ fragWp, unsigned short* __restrict__ fragWq,
    int* __restrict__ offs)
{
  const int b = blockIdx.x, t = threadIdx.x;
  if (b < 96) {
    __shared__ unsigned short lds[4096];
    const int c = b / 6, w = b - c * 6;
    const int colbase = w * 512 + c * 32;
    const int cl = t & 31, dg = t >> 5;
#pragma unroll
    for (int i = 0; i < 8; ++i) {
      const int d = dg * 8 + i;
      const float v = Wp[(size_t)d * 3072 + colbase + cl];
      const unsigned short hi = f2bf(v);
      const unsigned short lo = f2bf(v - bf2f(hi));
      const int ks = d >> 4;
      const int lane = ((d >> 3) & 1) * 32 + cl;
      const int j = d & 7;
      lds[(ks * 2 + 0) * 512 + lane * 8 + j] = hi;
      lds[(ks * 2 + 1) * 512 + lane * 8 + j] = lo;
    }
    __syncthreads();
    unsigned short* dst = fragWp + (size_t)b * 4096;
    ((uint4*)dst)[t] = ((const uint4*)lds)[t];
    ((uint4*)dst)[t + 256] = ((const uint4*)lds)[t + 256];
  } else if (b < 103) {
    const int slot = b - 96;
    const int w = (slot == 6) ? 5 : slot;
    const float sgn = (slot == 6) ? -1.f : 1.f;
    for (int tt = t; tt < 512; tt += 256) {
      const int lane = tt >> 3, j = tt & 7;
      const int o = lane & 31, c = (lane >> 5) * 8 + j;
      const float v = sgn * Wq[(size_t)(w * 16 + c) * 32 + o];
      const unsigned short hi = f2bf(v);
      const unsigned short lo = f2bf(v - bf2f(hi));
      fragWq[slot * 1024 + lane * 8 + j] = hi;
      fragWq[slot * 1024 + 512 + lane * 8 + j] = lo;
    }
  } else {
    const int tg = (b - 103) * 256 + t;
    if (tg >= E_TOTAL) return;
    const int cur = index[tg];
    const int prev = (tg == 0) ? -1 : index[tg - 1];
    for (int n = prev + 1; n <= cur; ++n) offs[n] = tg;
    if (tg == E_TOTAL - 1)
      for (int n = cur + 1; n <= NUM_NODES; ++n) offs[n] = E_TOTAL;
  }
}

// ---------------------------------------------------------------------------
// Main: 4 waves/block, 64 edges/block. Wave pair pg owns 32 edges; waves in a
// pair split n-tiles by parity (pr0: w even, pr1: w odd; z linear in k).
// A-fragments loaded DIRECTLY global->VGPR (L1/L2-resident, coalesced 1 KB),
// register ping-pong prefetch, ZERO barriers in the K-loop.
// ---------------------------------------------------------------------------
__global__ __launch_bounds__(256, 2) void main_kernel(
    const float* __restrict__ x_q, const float* __restrict__ x_k,
    const float* __restrict__ emb,
    const unsigned short* __restrict__ fragWp,
    const unsigned short* __restrict__ fragWq,
    float* __restrict__ z)
{
  __shared__ float xk_t[64][65];   // 16.25 KB, padded
  __shared__ float zred[4][32][4]; // 2 KB

  const int t = threadIdx.x;
  const int lane = t & 63, wv = t >> 6;
  const int pr = wv & 1;
  const int col = lane & 31, half = lane >> 5;
  const int eb = blockIdx.x * 64;
  const int el = (wv >> 1) * 32 + col;
  const int e = eb + el;

  // stage x_k transposed: thread t -> edge t>>2, d-quarter (t&3)*16
  {
    const int er = t >> 2, dq = (t & 3) * 16;
    const float* src = x_k + (size_t)(eb + er) * 64 + dq;
#pragma unroll
    for (int i = 0; i < 4; ++i) {
      float4 v = *(const float4*)(src + i * 4);
      xk_t[dq + i * 4 + 0][er] = v.x;
      xk_t[dq + i * 4 + 1][er] = v.y;
      xk_t[dq + i * 4 + 2][er] = v.z;
      xk_t[dq + i * 4 + 3][er] = v.w;
    }
  }

  // emb B-fragments hi/lo: B[k=d][col=e], d = ks*16 + half*8 + j
  bfrag ebh[4], ebl[4];
#pragma unroll
  for (int ks = 0; ks < 4; ++ks) {
    float tmp[8];
    *(float4*)&tmp[0] = *(const float4*)(emb + (size_t)e * 64 + ks * 16 + half * 8);
    *(float4*)&tmp[4] = *(const float4*)(emb + (size_t)e * 64 + ks * 16 + half * 8 + 4);
    cvt8(tmp, ebh[ks], ebl[ks]);
  }

  facc ka0 = {0}, ka1 = {0}, ka2 = {0}, ka3 = {0};

  // per-wave A stream: tile it lives at fbase + it*8192 (nt = it*2 + pr)
  const unsigned short* fbase = fragWp + pr * 4096 + lane * 8;

  bfrag curh[4], curl[4], nxth[4], nxtl[4];
#pragma unroll
  for (int ks = 0; ks < 4; ++ks) {
    *(uint4*)&curh[ks] = *(const uint4*)(fbase + ks * 1024);
    *(uint4*)&curl[ks] = *(const uint4*)(fbase + ks * 1024 + 512);
  }

  __syncthreads();  // xk_t ready (only barrier before the end)

  float xkc0 = 0.f, xkc1 = 0.f, xkc2 = 0.f, xkc3 = 0.f;

#pragma unroll 6
  for (int it = 0; it < 48; ++it) {
    const int j = it % 3;          // static under unroll-6
    // prefetch next tile's 8 frags into the other register set
    {
      const int itn = (it < 47) ? it + 1 : 47;
      const unsigned short* gp = fbase + (size_t)itn * 8192;
#pragma unroll
      for (int ks = 0; ks < 4; ++ks) {
        *(uint4*)&nxth[ks] = *(const uint4*)(gp + ks * 1024);
        *(uint4*)&nxtl[ks] = *(const uint4*)(gp + ks * 1024 + 512);
      }
    }
    if (j == 0) {
      const int c16 = it / 3;
      xkc0 = xk_t[c16][el];
      xkc1 = xk_t[16 + c16][el];
      xkc2 = xk_t[32 + c16][el];
      xkc3 = xk_t[48 + c16][el];
    }
    facc cc0 = {0.f}, cc1 = {0.f}, cc2 = {0.f};  // 3 independent chains of 4
#pragma unroll
    for (int ks = 0; ks < 4; ++ks) {
      cc0 = __builtin_amdgcn_mfma_f32_32x32x16_bf16(curh[ks], ebh[ks], cc0, 0, 0, 0);
      cc1 = __builtin_amdgcn_mfma_f32_32x32x16_bf16(curh[ks], ebl[ks], cc1, 0, 0, 0);
      cc2 = __builtin_amdgcn_mfma_f32_32x32x16_bf16(curl[ks], ebh[ks], cc2, 0, 0, 0);
    }
    // so2 contraction. pr0: w0:x0->m0 w2:x2->m0 w4:x1->m1,x3->m3
    //                  pr1: w1:x0->m2 w3:x2->m2 w5:x3->m1,-x1->m3
    if (j < 2) {
      const float xv = (j == 0) ? xkc0 : xkc2;
      if (pr == 0) {
#pragma unroll
        for (int r = 0; r < 16; ++r)
          ka0[r] = fmaf(xv, cc0[r] + cc1[r] + cc2[r], ka0[r]);
      } else {
#pragma unroll
        for (int r = 0; r < 16; ++r)
          ka2[r] = fmaf(xv, cc0[r] + cc1[r] + cc2[r], ka2[r]);
      }
    } else {
      if (pr == 0) {
#pragma unroll
        for (int r = 0; r < 16; ++r) {
          const float s = cc0[r] + cc1[r] + cc2[r];
          ka1[r] = fmaf(xkc1, s, ka1[r]);
          ka3[r] = fmaf(xkc3, s, ka3[r]);
        }
      } else {
#pragma unroll
        for (int r = 0; r < 16; ++r) {
          const float s = cc0[r] + cc1[r] + cc2[r];
          ka1[r] = fmaf(xkc3, s, ka1[r]);
          ka3[r] = fmaf(-xkc1, s, ka3[r]);
        }
      }
    }
    // rotate prefetch registers (coalesced away by regalloc under unroll)
#pragma unroll
    for (int ks = 0; ks < 4; ++ks) { curh[ks] = nxth[ks]; curl[ks] = nxtl[ks]; }
  }

  // ---- q via MFMA (same C layout as ka), partial z, cross-parity reduce
  bfrag xqh[4], xql[4];
#pragma unroll
  for (int a = 0; a < 4; ++a) {
    float tmp[8];
    *(float4*)&tmp[0] = *(const float4*)(x_q + (size_t)e * 64 + a * 16 + half * 8);
    *(float4*)&tmp[4] = *(const float4*)(x_q + (size_t)e * 64 + a * 16 + half * 8 + 4);
    cvt8(tmp, xqh[a], xql[a]);
  }
  float zp0 = 0.f, zp1 = 0.f, zp2 = 0.f, zp3 = 0.f;
  const int QA1[4] = {0, 1, 0, 3}, QS1[4] = {0, 4, 1, 4};
  const int QA2[4] = {2, 3, 2, 1}, QS2[4] = {2, 5, 3, 6};  // slot 6 = -Wq[5]
#pragma unroll
  for (int m = 0; m < 4; ++m) {
    facc qa = {0.f};
#pragma unroll
    for (int tm = 0; tm < 2; ++tm) {
      const int a = tm ? QA2[m] : QA1[m];
      const int sl = tm ? QS2[m] : QS1[m];
      bfrag wh, wl;
      *(uint4*)&wh = *(const uint4*)(fragWq + sl * 1024 + lane * 8);
      *(uint4*)&wl = *(const uint4*)(fragWq + sl * 1024 + 512 + lane * 8);
      qa = __builtin_amdgcn_mfma_f32_32x32x16_bf16(wh, xqh[a], qa, 0, 0, 0);
      qa = __builtin_amdgcn_mfma_f32_32x32x16_bf16(wh, xql[a], qa, 0, 0, 0);
      qa = __builtin_amdgcn_mfma_f32_32x32x16_bf16(wl, xqh[a], qa, 0, 0, 0);
    }
    const facc& km = (m == 0) ? ka0 : (m == 1) ? ka1 : (m == 2) ? ka2 : ka3;
#pragma unroll
    for (int r = 0; r < 16; ++r) {
      const float v = qa[r] * km[r];
      if (r < 4) zp0 += v;
      else if (r < 8) zp1 += v;
      else if (r < 12) zp2 += v;
      else zp3 += v;
    }
  }
  zp0 += __shfl_xor(zp0, 32);
  zp1 += __shfl_xor(zp1, 32);
  zp2 += __shfl_xor(zp2, 32);
  zp3 += __shfl_xor(zp3, 32);
  if (half == 0) {
    float4 v = {zp0, zp1, zp2, zp3};
    *(float4*)&zred[wv][col][0] = v;
  }
  __syncthreads();
  if (pr == 0 && half == 0) {
    float4 a = *(const float4*)&zred[wv][col][0];
    float4 b = *(const float4*)&zred[wv ^ 1][col][0];
    float4 o = {(a.x + b.x) * SCALE, (a.y + b.y) * SCALE,
                (a.z + b.z) * SCALE, (a.w + b.w) * SCALE};
    *(float4*)&z[(size_t)e * 4] = o;
  }
}

// ---------------------------------------------------------------------------
__global__ __launch_bounds__(256) void softmax_kernel(
    const float* __restrict__ z, const int* __restrict__ offs,
    float* __restrict__ out)
{
  const int node = blockIdx.x * 4 + (threadIdx.x >> 6);
  const int lane = threadIdx.x & 63;
  const int start = offs[node], end = offs[node + 1];
  if (start >= end) return;
  const int h = lane & 3, eo = lane >> 2;
  float m = -INFINITY;
  for (int e = start + eo; e < end; e += 16) m = fmaxf(m, z[(size_t)e * 4 + h]);
#pragma unroll
  for (int s = 4; s < 64; s <<= 1) m = fmaxf(m, __shfl_xor(m, s));
  float sum = 0.f;
  for (int e = start + eo; e < end; e += 16) sum += __expf(z[(size_t)e * 4 + h] - m);
#pragma unroll
  for (int s = 4; s < 64; s <<= 1) sum += __shfl_xor(sum, s);
  const float inv = 1.f / sum;
  for (int e = start + eo; e < end; e += 16)
    out[(size_t)e * 4 + h] = __expf(z[(size_t)e * 4 + h] - m) * inv;
}

extern "C" void kernel_launch(void* const* d_in, const int* in_sizes, int n_in,
                              void* d_out, int out_size, void* d_ws, size_t ws_size,
                              hipStream_t stream) {
  const float* x_q = (const float*)d_in[0];
  const float* x_k = (const float*)d_in[1];
  const float* emb = (const float*)d_in[2];
  const int* index = (const int*)d_in[3];
  const float* W_q = (const float*)d_in[4];
  const float* W_p = (const float*)d_in[5];
  float* out = (float*)d_out;

  char* ws = (char*)d_ws;
  float* z = (float*)ws;                                                    // 524288 B
  int* offs = (int*)(ws + 524288);                                          // 16388 B (pad 32 KB)
  unsigned short* fragWp = (unsigned short*)(ws + 524288 + 32768);          // 786432 B
  unsigned short* fragWq = (unsigned short*)(ws + 524288 + 32768 + 786432); // 14336 B

  prep_kernel<<<231, 256, 0, stream>>>(W_p, W_q, index, fragWp, fragWq, offs);
  main_kernel<<<512, 256, 0, stream>>>(x_q, x_k, emb, fragWp, fragWq, z);
  softmax_kernel<<<1024, 256, 0, stream>>>(z, offs, out);
}